// Round 12
// baseline (844.808 us; speedup 1.0000x reference)
//
#include <hip/hip_runtime.h>

#define N_TOK 32768
#define N_EMB 4096
#define DIM 256

typedef short bf16x8 __attribute__((ext_vector_type(8)));
typedef float f32x4 __attribute__((ext_vector_type(4)));
typedef unsigned short us8 __attribute__((ext_vector_type(8)));

// ---------------- ws layout (primary, ws_size >= 20 MB) ----------------
// [0, 16384)        counts    uint[4096]
// [16384, 16388)    loss_acc  float
// [16896, 33280)    e2_np     float[4096]
// [17 MB, 19 MB)    Wh        bf16[4096*256]  MFMA-shuffled
// Fallback (small ws): Wh in encodings region + separate k_onehot.

static __device__ __forceinline__ unsigned short f2bf(float f) {
    unsigned int u = __float_as_uint(f);
    u = (u + 0x7fffu + ((u >> 16) & 1u)) >> 16;   // RTN-even
    return (unsigned short)u;
}

// ---------------- numpy-pairwise fp32 row norms (r3-proven bit-exact) ------
__device__ __forceinline__ float pw128_sq(const float4* a4) {
#pragma clang fp contract(off)
    float4 v0 = a4[0], v1 = a4[1];
    float r0 = v0.x * v0.x, r1 = v0.y * v0.y, r2 = v0.z * v0.z, r3 = v0.w * v0.w;
    float r4 = v1.x * v1.x, r5 = v1.y * v1.y, r6 = v1.z * v1.z, r7 = v1.w * v1.w;
    #pragma unroll
    for (int i = 1; i < 16; ++i) {
        v0 = a4[2 * i]; v1 = a4[2 * i + 1];
        float s;
        s = v0.x * v0.x; r0 += s;
        s = v0.y * v0.y; r1 += s;
        s = v0.z * v0.z; r2 += s;
        s = v0.w * v0.w; r3 += s;
        s = v1.x * v1.x; r4 += s;
        s = v1.y * v1.y; r5 += s;
        s = v1.z * v1.z; r6 += s;
        s = v1.w * v1.w; r7 += s;
    }
    return ((r0 + r1) + (r2 + r3)) + ((r4 + r5) + (r6 + r7));
}

// ---- Wh-only prep: bf16 MFMA-shuffle + bit-exact row norms (r8-verified) ----
__global__ __launch_bounds__(256) void k_prep_w(const float* __restrict__ w,
                                                unsigned short* __restrict__ Wh,
                                                float* __restrict__ e2_np) {
    const int T = blockIdx.x;
    const int t = threadIdx.x, lane = t & 63, g = t >> 6;
    #pragma unroll
    for (int cc = 0; cc < 2; ++cc) {
        int C = g * 2 + cc;
        int row = T * 16 + (lane & 15);
        int col = C * 32 + (lane >> 4) * 8;
        const float* s = w + (size_t)row * DIM + col;
        us8 h;
        #pragma unroll
        for (int j = 0; j < 8; ++j) h[j] = f2bf(s[j]);
        *(us8*)(Wh + ((size_t)(T * 8 + C) * 64 + lane) * 8) = h;
    }
    if (t < 16) {
        int row = T * 16 + t;
        const float4* a = (const float4*)(w + (size_t)row * DIM);
        float lo = pw128_sq(a);
        float hi = pw128_sq(a + 32);
        e2_np[row] = lo + hi;
    }
}

// ---- fused MFMA scoring: 64 tokens/block, 8 waves, 512 blocks. ----
// Evidence chain: r9 (stagger null, FETCH flat), r10 (manual MLP -27us),
// r11 (occupancy 44.6->58.6% with time FLAT and FETCH 455->691 MB) => the
// jt loop is REUSE-DISTANCE bound: 1024 concurrent Wh sweep-streams thrash
// the per-XCD L2 under enc-write pressure. This config holds the proven
// 16 waves/CU (2 blocks x 8 waves) while HALVING the stream count (512
// blocks, 1 GB total Wh L2 demand) and DOUBLING MFMA work per bh load
// (m=4 tiles x n=2 slices per wave). All r8 machinery verbatim otherwise:
// self-stage layout, drip 8x16B/thread/tile, branchy top-2 (1.5e-4 margin,
// now 32 cands/thread -> strictly safer), np-exact refine.
__global__ __launch_bounds__(512, 4) void k_score_mfma(
        const float* __restrict__ x, const float* __restrict__ w,
        const float* __restrict__ e2_np,
        const unsigned short* __restrict__ Wh,
        float* __restrict__ out_idx, unsigned int* __restrict__ counts,
        float* enc,                       // nullable: fused one-hot
        float* __restrict__ outq, float* __restrict__ loss_acc) {
    __shared__ __align__(16) short Abuf[16384];  // [tile(4)][C(8)][lane][8] = 32 KB
    __shared__ float x2s[64];
    __shared__ float Tmax[8][64];
    __shared__ unsigned int ccnt[64];
    __shared__ int clist[64][16];
    __shared__ float Red_d[64 * 8];
    __shared__ int   Red_i[64 * 8];
    __shared__ float sred[8];

    const int t = threadIdx.x;
    const int wave = t >> 6, lane = t & 63;
    const int tok0 = blockIdx.x * 64;
    const int q = lane >> 4, c = lane & 15;

    // ---- self-stage A: thread t -> row t>>3 (0..63), 32-float segment t&7 ----
    // (r8-verified index-identical to k_shuf1 + global_load_lds composition)
    {
        int row = t >> 3, seg = t & 7;
        const float* xr = x + (size_t)(tok0 + row) * DIM + seg * 32;
        int base = ((row >> 4) * 8 + seg) * 64;
        int l16 = row & 15;
        #pragma unroll
        for (int j = 0; j < 4; ++j) {
            float4 a = *(const float4*)(xr + j * 8);
            float4 b = *(const float4*)(xr + j * 8 + 4);
            us8 h;
            h[0] = f2bf(a.x); h[1] = f2bf(a.y); h[2] = f2bf(a.z); h[3] = f2bf(a.w);
            h[4] = f2bf(b.x); h[5] = f2bf(b.y); h[6] = f2bf(b.z); h[7] = f2bf(b.w);
            *(us8*)(Abuf + ((size_t)(base + j * 16 + l16)) * 8) = h;
        }
    }
    if (t < 64) {
        ccnt[t] = 0;
        // bit-exact np row norm on L1-hot row
        const float4* a = (const float4*)(x + (size_t)(tok0 + t) * DIM);
        float lo = pw128_sq(a);
        float hi = pw128_sq(a + 32);
        x2s[t] = lo + hi;
    }
    __syncthreads();

    f32x4* ez = enc ? (f32x4*)(enc + (size_t)tok0 * N_EMB) : (f32x4*)0;
    const f32x4 zf4 = {0.f, 0.f, 0.f, 0.f};

    // ---- single pass: per-token packed top-2; one-hot zero-fill drip-fed ----
    float vmax[16], v2[16];
    #pragma unroll
    for (int s = 0; s < 16; ++s) { vmax[s] = -3.4e38f; v2[s] = -3.4e38f; }
    for (int jt = 0; jt < N_EMB; jt += 256) {
        const int U0 = (jt >> 4) + wave * 2;     // this wave's 2 16-code blocks
        f32x4 acc[4][2] = {};
        #pragma unroll
        for (int C = 0; C < 8; ++C) {
            bf16x8 ah[4], bh[2];
            #pragma unroll
            for (int m = 0; m < 4; ++m)
                ah[m] = *(const bf16x8*)(Abuf + (size_t)(m * 8 + C) * 512 + lane * 8);
            #pragma unroll
            for (int n = 0; n < 2; ++n)
                bh[n] = *(const bf16x8*)(Wh + (((size_t)(U0 + n) * 8 + C) * 64 + lane) * 8);
            #pragma unroll
            for (int m = 0; m < 4; ++m)
                #pragma unroll
                for (int n = 0; n < 2; ++n)
                    acc[m][n] = __builtin_amdgcn_mfma_f32_16x16x32_bf16(ah[m], bh[n], acc[m][n], 0, 0, 0);
        }
        // packed top-2 update: low bits carry (jtTile<<1 | n), <=64 ulp
        {
            unsigned int idb = ((unsigned int)jt >> 8) << 1;
            #pragma unroll
            for (int m = 0; m < 4; ++m)
                #pragma unroll
                for (int n = 0; n < 2; ++n)
                    #pragma unroll
                    for (int r = 0; r < 4; ++r) {
                        float p = __uint_as_float(
                            (__float_as_uint(acc[m][n][r]) & ~63u) | (idb + (unsigned)n));
                        int s = m * 4 + r;
                        if (p > vmax[s]) { v2[s] = vmax[s]; vmax[s] = p; }
                        else if (p > v2[s]) v2[s] = p;
                    }
        }
        if (ez) {   // 8 x 16B nt zero-stores per thread per jt = 64 KB/block/tile
            int base = (jt >> 8) * 4096 + t;
            #pragma unroll
            for (int j = 0; j < 8; ++j)
                __builtin_nontemporal_store(zf4, ez + base + j * 512);
        }
    }
    // reduce over the 16 c-lanes of each q-group (keep per-thread vmax/v2!)
    float rmax[16];
    #pragma unroll
    for (int s = 0; s < 16; ++s) rmax[s] = vmax[s];
    #pragma unroll
    for (int off = 1; off < 16; off <<= 1)
        #pragma unroll
        for (int s = 0; s < 16; ++s)
            rmax[s] = fmaxf(rmax[s], __shfl_xor(rmax[s], off));
    if (c == 0) {
        #pragma unroll
        for (int m = 0; m < 4; ++m)
            #pragma unroll
            for (int r = 0; r < 4; ++r)
                Tmax[wave][m * 16 + q * 4 + r] = rmax[m * 4 + r];
    }
    __syncthreads();
    if (t < 64) {
        float mx = Tmax[0][t];
        #pragma unroll
        for (int w2 = 1; w2 < 8; ++w2) mx = fmaxf(mx, Tmax[w2][t]);
        Tmax[0][t] = mx - 1.5e-4f;     // threshold (r6/r7-proven margin)
    }
    __syncthreads();
    float thr[16];
    #pragma unroll
    for (int m = 0; m < 4; ++m)
        #pragma unroll
        for (int r = 0; r < 4; ++r)
            thr[m * 4 + r] = Tmax[0][m * 16 + q * 4 + r];

    // ---- candidate push from registers (no recompute pass) ----
    #pragma unroll
    for (int s = 0; s < 16; ++s) {
        int m = s >> 2, r = s & 3;
        int tokl = m * 16 + q * 4 + r;
        #pragma unroll
        for (int h = 0; h < 2; ++h) {
            float pv = h ? v2[s] : vmax[s];
            if (pv >= thr[s]) {
                unsigned int id = __float_as_uint(pv) & 63u;
                int code = ((int)(id >> 1) * 16 + wave * 2 + (int)(id & 1u)) * 16 + c;
                unsigned int p = atomicAdd(&ccnt[tokl], 1u);
                if (p < 16) clist[tokl][p] = code;
            }
        }
    }
    __syncthreads();

    // ---- np-fp32-exact refinement: 8 threads/token over the list ----
    {
        int token = t >> 3, slot = t & 7;
        int cnt = (int)ccnt[token]; if (cnt > 16) cnt = 16;
        float bd = 3.4e38f;
        int bi = 0x7fffffff;
        float x2 = x2s[token];
        const float4* xr = (const float4*)(x + (size_t)(tok0 + token) * DIM);
        for (int k = slot; k < cnt; k += 8) {
            int code = clist[token][k];
            const float4* wr = (const float4*)(w + (size_t)code * DIM);
            double dot = 0.0;
            for (int g = 0; g < 64; ++g) {
                float4 xv = xr[g];
                float4 wv = wr[g];
                dot += (double)xv.x * (double)wv.x;
                dot += (double)xv.y * (double)wv.y;
                dot += (double)xv.z * (double)wv.z;
                dot += (double)xv.w * (double)wv.w;
            }
            {
#pragma clang fp contract(off)
                float M  = (float)dot;          // BLAS sgemm entry (~2e-9)
                float S  = x2 + e2_np[code];    // np broadcast add (fp32)
                float dd = S - 2.0f * M;        // fp32 sub -> ulp bucket
                if (dd < bd || (dd == bd && code < bi)) { bd = dd; bi = code; }
            }
        }
        Red_d[token * 8 + slot] = bd;
        Red_i[token * 8 + slot] = bi;
    }
    __syncthreads();
    if (t < 64) {
        float fv = Red_d[t * 8];
        int   fi = Red_i[t * 8];
        #pragma unroll
        for (int k = 1; k < 8; ++k) {
            float v = Red_d[t * 8 + k];
            int  ii = Red_i[t * 8 + k];
            if (v < fv || (v == fv && ii < fi)) { fv = v; fi = ii; }
        }
        out_idx[tok0 + t] = (float)fi;
        atomicAdd(&counts[fi], 1u);
        ccnt[t] = (unsigned int)fi;   // publish for epilogue
    }
    __syncthreads();

    // ---- epilogue: 1.0f scatter + quantized gather + commitment loss ----
    {
        int token = t >> 3, slot = t & 7;
        int fi = (int)ccnt[token];
        // zero-stores for this row drained at the Tmax __syncthreads (vmcnt(0));
        // same-XCD L2 ordering makes this 1.0f land after them.
        if (enc && slot == 0)
            __builtin_nontemporal_store(1.0f, enc + (size_t)(tok0 + token) * N_EMB + fi);
        const f32x4* wr = (const f32x4*)(w + (size_t)fi * DIM);
        const f32x4* xr = (const f32x4*)(x + (size_t)(tok0 + token) * DIM);
        f32x4* oq = (f32x4*)(outq + (size_t)(tok0 + token) * DIM);
        float sse = 0.f;
        #pragma unroll
        for (int g0 = 0; g0 < 8; ++g0) {
            int g = slot * 8 + g0;
            f32x4 qv = wr[g];
            f32x4 xv = xr[g];
            __builtin_nontemporal_store(qv, oq + g);
            float dx = qv.x - xv.x, dy = qv.y - xv.y;
            float dz = qv.z - xv.z, dw = qv.w - xv.w;
            sse += dx * dx + dy * dy + dz * dz + dw * dw;
        }
        #pragma unroll
        for (int off = 32; off > 0; off >>= 1) sse += __shfl_down(sse, off, 64);
        if (lane == 0) sred[wave] = sse;
    }
    __syncthreads();
    if (t == 0) {
        float s = 0.f;
        #pragma unroll
        for (int w2 = 0; w2 < 8; ++w2) s += sred[w2];
        atomicAdd(loss_acc, s);
    }
}

// ---------------- one-hot encodings (fallback path only) ----------------
__global__ __launch_bounds__(256) void k_onehot(const float* __restrict__ out_idx,
                                                float* __restrict__ enc) {
    int token = blockIdx.x;
    int idx = (int)out_idx[token];
    float4* row = (float4*)(enc + (size_t)token * N_EMB);
    #pragma unroll
    for (int p = 0; p < 4; ++p) {
        int g = threadIdx.x + 256 * p;
        float4 v = make_float4(0.f, 0.f, 0.f, 0.f);
        int d0 = g * 4;
        if (idx >= d0 && idx < d0 + 4) ((float*)&v)[idx - d0] = 1.0f;
        row[g] = v;
    }
}

// ---------------- perplexity + loss finalize ----------------
__global__ __launch_bounds__(256) void k_final(const unsigned int* __restrict__ counts,
                                               const float* __restrict__ loss_acc,
                                               float* __restrict__ out_perp,
                                               float* __restrict__ out_loss) {
    __shared__ float sred[4];
    int t = threadIdx.x;
    float h = 0.f;
    for (int k = t; k < N_EMB; k += 256) {
        float p = (float)counts[k] * (1.0f / N_TOK);
        h += p * logf(p + 1e-10f);
    }
    #pragma unroll
    for (int off = 32; off > 0; off >>= 1) h += __shfl_down(h, off, 64);
    if ((t & 63) == 0) sred[t >> 6] = h;
    __syncthreads();
    if (t == 0) {
        float s = sred[0] + sred[1] + sred[2] + sred[3];
        *out_perp = expf(-s);
        *out_loss = loss_acc[0] * 1.25f / 8388608.0f;
    }
}

extern "C" void kernel_launch(void* const* d_in, const int* in_sizes, int n_in,
                              void* d_out, int out_size, void* d_ws, size_t ws_size,
                              hipStream_t stream) {
    const float* x = (const float*)d_in[0];
    const float* w = (const float*)d_in[1];
    float* out  = (float*)d_out;
    float* out0 = out;                       // quantized_st [32768*256]
    float* out1 = out0 + 8388608;            // perplexity   [1]
    float* out2 = out1 + 1;                  // encodings    [32768*4096]
    float* out3 = out2 + 134217728;          // indices      [32768] (as float)
    float* out4 = out3 + 32768;              // loss         [1]

    unsigned int* counts = (unsigned int*)d_ws;
    float* loss_acc = (float*)((char*)d_ws + 16384);
    float* e2_np    = (float*)((char*)d_ws + 16896);

    // Primary: Wh in d_ws, enc zeroed by the drip inside the score jt-loop +
    // 1.0f scatter. Fallback (small ws): Wh aliases out2 -> no fused enc,
    // full-row k_onehot after score.
    bool big_ws = ws_size >= (size_t)(20u * 1024u * 1024u);
    unsigned short* Wh;
    float* enc_arg;
    if (big_ws) {
        Wh = (unsigned short*)((char*)d_ws + 17u * 1024u * 1024u);   // 2 MB
        enc_arg = out2;
    } else {
        uintptr_t sb = ((uintptr_t)out2 + 255) & ~(uintptr_t)255;
        Wh = (unsigned short*)sb;
        enc_arg = nullptr;
    }

    hipMemsetAsync(d_ws, 0, 16640, stream);
    k_prep_w<<<N_EMB / 16, 256, 0, stream>>>(w, Wh, e2_np);
    k_score_mfma<<<N_TOK / 64, 512, 0, stream>>>(x, w, e2_np, Wh,
                                                 out3, counts, enc_arg,
                                                 out0, loss_acc);
    if (!big_ws)
        k_onehot<<<N_TOK, 256, 0, stream>>>(out3, out2);
    k_final<<<1, 256, 0, stream>>>(counts, loss_acc, out1, out4);
}

// Round 13
// 685.778 us; speedup vs baseline: 1.2319x; 1.2319x over previous
//
#include <hip/hip_runtime.h>

#define N_TOK 32768
#define N_EMB 4096
#define DIM 256
#define NSTEP 128

typedef short bf16x8 __attribute__((ext_vector_type(8)));
typedef float f32x4 __attribute__((ext_vector_type(4)));
typedef unsigned short us8 __attribute__((ext_vector_type(8)));

// ---------------- ws layout (primary, ws_size >= 20 MB) ----------------
// [0, 16384)        counts    uint[4096]
// [16384, 16388)    loss_acc  float
// [16896, 33280)    e2_np     float[4096]
// [17 MB, 19 MB)    Wh        bf16[4096*256]  MFMA-shuffled
// Fallback (small ws): Wh in encodings region + separate k_onehot.

static __device__ __forceinline__ unsigned short f2bf(float f) {
    unsigned int u = __float_as_uint(f);
    u = (u + 0x7fffu + ((u >> 16) & 1u)) >> 16;   // RTN-even
    return (unsigned short)u;
}

// ---------------- numpy-pairwise fp32 row norms (r3-proven bit-exact) ------
__device__ __forceinline__ float pw128_sq(const float4* a4) {
#pragma clang fp contract(off)
    float4 v0 = a4[0], v1 = a4[1];
    float r0 = v0.x * v0.x, r1 = v0.y * v0.y, r2 = v0.z * v0.z, r3 = v0.w * v0.w;
    float r4 = v1.x * v1.x, r5 = v1.y * v1.y, r6 = v1.z * v1.z, r7 = v1.w * v1.w;
    #pragma unroll
    for (int i = 1; i < 16; ++i) {
        v0 = a4[2 * i]; v1 = a4[2 * i + 1];
        float s;
        s = v0.x * v0.x; r0 += s;
        s = v0.y * v0.y; r1 += s;
        s = v0.z * v0.z; r2 += s;
        s = v0.w * v0.w; r3 += s;
        s = v1.x * v1.x; r4 += s;
        s = v1.y * v1.y; r5 += s;
        s = v1.z * v1.z; r6 += s;
        s = v1.w * v1.w; r7 += s;
    }
    return ((r0 + r1) + (r2 + r3)) + ((r4 + r5) + (r6 + r7));
}

// ---- Wh-only prep: bf16 MFMA-shuffle + bit-exact row norms (r8-verified) ----
__global__ __launch_bounds__(256) void k_prep_w(const float* __restrict__ w,
                                                unsigned short* __restrict__ Wh,
                                                float* __restrict__ e2_np) {
    const int T = blockIdx.x;
    const int t = threadIdx.x, lane = t & 63, g = t >> 6;
    #pragma unroll
    for (int cc = 0; cc < 2; ++cc) {
        int C = g * 2 + cc;
        int row = T * 16 + (lane & 15);
        int col = C * 32 + (lane >> 4) * 8;
        const float* s = w + (size_t)row * DIM + col;
        us8 h;
        #pragma unroll
        for (int j = 0; j < 8; ++j) h[j] = f2bf(s[j]);
        *(us8*)(Wh + ((size_t)(T * 8 + C) * 64 + lane) * 8) = h;
    }
    if (t < 16) {
        int row = T * 16 + t;
        const float4* a = (const float4*)(w + (size_t)row * DIM);
        float lo = pw128_sq(a);
        float hi = pw128_sq(a + 32);
        e2_np[row] = lo + hi;
    }
}

// ---- fused MFMA scoring: canonical double-buffered LDS GEMM loop. ----
// r9-r12 falsified phase/MLP/occupancy/stream-count theories; invariant:
// per-wave global bh loads on the MFMA critical path (208 TF effective).
// This applies the m97-proven recipe: per 32-code N-step, stage 16 KB of Wh
// into LDS via async global_load_lds (double-buffered: step s+1 staged at
// top of step s compute, drained by the end-of-step __syncthreads), MFMA
// reads bh from LDS. A-fragments hoisted to registers (wave owns one
// (m-tile, n-half); Abuf deleted -> 37 KB LDS, 4 blocks/CU = r8's proven
// 16 waves/CU). Top-2 per lane over its 128-code stream, 7-bit step id in
// low mantissa (<=127 ulp << 1.5e-4 margin). Drip 1 NT store/thread/step
// (same 512 KB). Refine/epilogue verbatim r8.
__global__ __launch_bounds__(256, 4) void k_score_mfma(
        const float* __restrict__ x, const float* __restrict__ w,
        const float* __restrict__ e2_np,
        const unsigned short* __restrict__ Wh,
        float* __restrict__ out_idx, unsigned int* __restrict__ counts,
        float* enc,                       // nullable: fused one-hot
        float* __restrict__ outq, float* __restrict__ loss_acc) {
    __shared__ __align__(16) short Bbuf[2][8192];   // 2 x 16 KB double buffer
    __shared__ float x2s[32];
    __shared__ float Tmax[2][32];
    __shared__ unsigned int ccnt[32];
    __shared__ int clist[32][16];
    __shared__ float Red_d[32 * 8];
    __shared__ int   Red_i[32 * 8];
    __shared__ float sred[4];

    const int t = threadIdx.x;
    const int wave = t >> 6, lane = t & 63;
    const int tok0 = blockIdx.x * 32;
    const int q = lane >> 4, c = lane & 15;
    const int mt = wave & 1, nb = wave >> 1;   // wave = (m-tile, n-half)

    // ---- stage step 0 into Bbuf[0] (async, drains at first barrier) ----
    {
        const unsigned short* sp = Wh + (size_t)wave * 512 + lane * 8;
        #pragma unroll
        for (int k = 0; k < 4; ++k)
            __builtin_amdgcn_global_load_lds(
                (const __attribute__((address_space(1))) unsigned int*)(sp + k * 2048),
                (__attribute__((address_space(3))) unsigned int*)(&Bbuf[0][wave * 512 + k * 2048]),
                16, 0, 0);
    }

    // ---- A-fragment hoist: per-lane direct global load + f2bf ----
    // ah[C][e] = bf16(x[(tok0 + mt*16 + c)*256 + C*32 + q*8 + e])
    // (identical element mapping to r8's Abuf composition, verified there)
    bf16x8 ah[8];
    {
        const float* xrow = x + (size_t)(tok0 + mt * 16 + c) * DIM + q * 8;
        #pragma unroll
        for (int C = 0; C < 8; ++C) {
            float4 a = *(const float4*)(xrow + C * 32);
            float4 b = *(const float4*)(xrow + C * 32 + 4);
            us8 h;
            h[0] = f2bf(a.x); h[1] = f2bf(a.y); h[2] = f2bf(a.z); h[3] = f2bf(a.w);
            h[4] = f2bf(b.x); h[5] = f2bf(b.y); h[6] = f2bf(b.z); h[7] = f2bf(b.w);
            ah[C] = *(bf16x8*)&h;
        }
    }
    if (t < 32) {
        ccnt[t] = 0;
        // bit-exact np row norm (row is L2-hot from the hoist)
        const float4* a = (const float4*)(x + (size_t)(tok0 + t) * DIM);
        float lo = pw128_sq(a);
        float hi = pw128_sq(a + 32);
        x2s[t] = lo + hi;
    }
    __syncthreads();   // step-0 tile staged; A hoisted; norms ready

    f32x4* ez = enc ? (f32x4*)(enc + (size_t)tok0 * N_EMB) : (f32x4*)0;
    const f32x4 zf4 = {0.f, 0.f, 0.f, 0.f};

    // ---- main loop: 128 N-steps of 32 codes, LDS double-buffered ----
    float vmax[4], v2[4];
    #pragma unroll
    for (int r = 0; r < 4; ++r) { vmax[r] = -3.4e38f; v2[r] = -3.4e38f; }
    for (int s = 0; s < NSTEP; ++s) {
        const int cur = s & 1;
        if (s + 1 < NSTEP) {   // stage next tile into the other buffer
            const unsigned short* sp = Wh + (size_t)(s + 1) * 8192 + wave * 512 + lane * 8;
            short* dp = &Bbuf[cur ^ 1][wave * 512];
            #pragma unroll
            for (int k = 0; k < 4; ++k)
                __builtin_amdgcn_global_load_lds(
                    (const __attribute__((address_space(1))) unsigned int*)(sp + k * 2048),
                    (__attribute__((address_space(3))) unsigned int*)(dp + k * 2048),
                    16, 0, 0);
        }
        if (ez)   // one-hot zero drip: 1 x 16B NT store/thread/step
            __builtin_nontemporal_store(zf4, ez + s * 256 + t);

        f32x4 acc = {};
        #pragma unroll
        for (int C = 0; C < 8; ++C) {
            bf16x8 bh = *(const bf16x8*)(&Bbuf[cur][((nb * 8 + C) * 64 + lane) * 8]);
            acc = __builtin_amdgcn_mfma_f32_16x16x32_bf16(ah[C], bh, acc, 0, 0, 0);
        }
        // packed top-2: low 7 mantissa bits carry the step id
        #pragma unroll
        for (int r = 0; r < 4; ++r) {
            float p = __uint_as_float(
                (__float_as_uint(acc[r]) & ~127u) | (unsigned)s);
            if (p > vmax[r]) { v2[r] = vmax[r]; vmax[r] = p; }
            else if (p > v2[r]) v2[r] = p;
        }
        __syncthreads();   // drains next-tile staging; all reads of cur done
    }

    // ---- reduce over the 16 c-lanes of each q-group ----
    float rmax[4];
    #pragma unroll
    for (int r = 0; r < 4; ++r) rmax[r] = vmax[r];
    #pragma unroll
    for (int off = 1; off < 16; off <<= 1)
        #pragma unroll
        for (int r = 0; r < 4; ++r)
            rmax[r] = fmaxf(rmax[r], __shfl_xor(rmax[r], off));
    if (c == 0) {
        #pragma unroll
        for (int r = 0; r < 4; ++r)
            Tmax[nb][mt * 16 + q * 4 + r] = rmax[r];
    }
    __syncthreads();
    if (t < 32)
        Tmax[0][t] = fmaxf(Tmax[0][t], Tmax[1][t]) - 1.5e-4f;  // threshold
    __syncthreads();
    float thr[4];
    #pragma unroll
    for (int r = 0; r < 4; ++r)
        thr[r] = Tmax[0][mt * 16 + q * 4 + r];

    // ---- candidate push from registers ----
    #pragma unroll
    for (int r = 0; r < 4; ++r) {
        int tokl = mt * 16 + q * 4 + r;
        #pragma unroll
        for (int h = 0; h < 2; ++h) {
            float pv = h ? v2[r] : vmax[r];
            if (pv >= thr[r]) {
                int sid = (int)(__float_as_uint(pv) & 127u);
                int code = sid * 32 + nb * 16 + c;
                unsigned int p = atomicAdd(&ccnt[tokl], 1u);
                if (p < 16) clist[tokl][p] = code;
            }
        }
    }
    __syncthreads();

    // ---- np-fp32-exact refinement: 8 threads/token over the list ----
    {
        int token = t >> 3, slot = t & 7;
        int cnt = (int)ccnt[token]; if (cnt > 16) cnt = 16;
        float bd = 3.4e38f;
        int bi = 0x7fffffff;
        float x2 = x2s[token];
        const float4* xr = (const float4*)(x + (size_t)(tok0 + token) * DIM);
        for (int k = slot; k < cnt; k += 8) {
            int code = clist[token][k];
            const float4* wr = (const float4*)(w + (size_t)code * DIM);
            double dot = 0.0;
            for (int g = 0; g < 64; ++g) {
                float4 xv = xr[g];
                float4 wv = wr[g];
                dot += (double)xv.x * (double)wv.x;
                dot += (double)xv.y * (double)wv.y;
                dot += (double)xv.z * (double)wv.z;
                dot += (double)xv.w * (double)wv.w;
            }
            {
#pragma clang fp contract(off)
                float M  = (float)dot;          // BLAS sgemm entry (~2e-9)
                float S  = x2 + e2_np[code];    // np broadcast add (fp32)
                float dd = S - 2.0f * M;        // fp32 sub -> ulp bucket
                if (dd < bd || (dd == bd && code < bi)) { bd = dd; bi = code; }
            }
        }
        Red_d[token * 8 + slot] = bd;
        Red_i[token * 8 + slot] = bi;
    }
    __syncthreads();
    if (t < 32) {
        float fv = Red_d[t * 8];
        int   fi = Red_i[t * 8];
        #pragma unroll
        for (int k = 1; k < 8; ++k) {
            float v = Red_d[t * 8 + k];
            int  ii = Red_i[t * 8 + k];
            if (v < fv || (v == fv && ii < fi)) { fv = v; fi = ii; }
        }
        out_idx[tok0 + t] = (float)fi;
        atomicAdd(&counts[fi], 1u);
        ccnt[t] = (unsigned int)fi;   // publish for epilogue
    }
    __syncthreads();

    // ---- epilogue: 1.0f scatter + quantized gather + commitment loss ----
    {
        int token = t >> 3, slot = t & 7;
        int fi = (int)ccnt[token];
        // zero-stores for this row drained at loop barriers (vmcnt(0));
        // same-XCD L2 ordering makes this 1.0f land after them.
        if (enc && slot == 0)
            __builtin_nontemporal_store(1.0f, enc + (size_t)(tok0 + token) * N_EMB + fi);
        const f32x4* wr = (const f32x4*)(w + (size_t)fi * DIM);
        const f32x4* xr = (const f32x4*)(x + (size_t)(tok0 + token) * DIM);
        f32x4* oq = (f32x4*)(outq + (size_t)(tok0 + token) * DIM);
        float sse = 0.f;
        #pragma unroll
        for (int g0 = 0; g0 < 8; ++g0) {
            int g = slot * 8 + g0;
            f32x4 qv = wr[g];
            f32x4 xv = xr[g];
            __builtin_nontemporal_store(qv, oq + g);
            float dx = qv.x - xv.x, dy = qv.y - xv.y;
            float dz = qv.z - xv.z, dw = qv.w - xv.w;
            sse += dx * dx + dy * dy + dz * dz + dw * dw;
        }
        #pragma unroll
        for (int off = 32; off > 0; off >>= 1) sse += __shfl_down(sse, off, 64);
        if (lane == 0) sred[wave] = sse;
    }
    __syncthreads();
    if (t == 0)
        atomicAdd(loss_acc, sred[0] + sred[1] + sred[2] + sred[3]);
}

// ---------------- one-hot encodings (fallback path only) ----------------
__global__ __launch_bounds__(256) void k_onehot(const float* __restrict__ out_idx,
                                                float* __restrict__ enc) {
    int token = blockIdx.x;
    int idx = (int)out_idx[token];
    float4* row = (float4*)(enc + (size_t)token * N_EMB);
    #pragma unroll
    for (int p = 0; p < 4; ++p) {
        int g = threadIdx.x + 256 * p;
        float4 v = make_float4(0.f, 0.f, 0.f, 0.f);
        int d0 = g * 4;
        if (idx >= d0 && idx < d0 + 4) ((float*)&v)[idx - d0] = 1.0f;
        row[g] = v;
    }
}

// ---------------- perplexity + loss finalize ----------------
__global__ __launch_bounds__(256) void k_final(const unsigned int* __restrict__ counts,
                                               const float* __restrict__ loss_acc,
                                               float* __restrict__ out_perp,
                                               float* __restrict__ out_loss) {
    __shared__ float sred[4];
    int t = threadIdx.x;
    float h = 0.f;
    for (int k = t; k < N_EMB; k += 256) {
        float p = (float)counts[k] * (1.0f / N_TOK);
        h += p * logf(p + 1e-10f);
    }
    #pragma unroll
    for (int off = 32; off > 0; off >>= 1) h += __shfl_down(h, off, 64);
    if ((t & 63) == 0) sred[t >> 6] = h;
    __syncthreads();
    if (t == 0) {
        float s = sred[0] + sred[1] + sred[2] + sred[3];
        *out_perp = expf(-s);
        *out_loss = loss_acc[0] * 1.25f / 8388608.0f;
    }
}

extern "C" void kernel_launch(void* const* d_in, const int* in_sizes, int n_in,
                              void* d_out, int out_size, void* d_ws, size_t ws_size,
                              hipStream_t stream) {
    const float* x = (const float*)d_in[0];
    const float* w = (const float*)d_in[1];
    float* out  = (float*)d_out;
    float* out0 = out;                       // quantized_st [32768*256]
    float* out1 = out0 + 8388608;            // perplexity   [1]
    float* out2 = out1 + 1;                  // encodings    [32768*4096]
    float* out3 = out2 + 134217728;          // indices      [32768] (as float)
    float* out4 = out3 + 32768;              // loss         [1]

    unsigned int* counts = (unsigned int*)d_ws;
    float* loss_acc = (float*)((char*)d_ws + 16384);
    float* e2_np    = (float*)((char*)d_ws + 16896);

    // Primary: Wh in d_ws, enc zeroed by the drip inside the score loop +
    // 1.0f scatter. Fallback (small ws): Wh aliases out2 -> no fused enc,
    // full-row k_onehot after score.
    bool big_ws = ws_size >= (size_t)(20u * 1024u * 1024u);
    unsigned short* Wh;
    float* enc_arg;
    if (big_ws) {
        Wh = (unsigned short*)((char*)d_ws + 17u * 1024u * 1024u);   // 2 MB
        enc_arg = out2;
    } else {
        uintptr_t sb = ((uintptr_t)out2 + 255) & ~(uintptr_t)255;
        Wh = (unsigned short*)sb;
        enc_arg = nullptr;
    }

    hipMemsetAsync(d_ws, 0, 16640, stream);
    k_prep_w<<<N_EMB / 16, 256, 0, stream>>>(w, Wh, e2_np);
    k_score_mfma<<<N_TOK / 32, 256, 0, stream>>>(x, w, e2_np, Wh,
                                                 out3, counts, enc_arg,
                                                 out0, loss_acc);
    if (!big_ws)
        k_onehot<<<N_TOK, 256, 0, stream>>>(out3, out2);
    k_final<<<1, 256, 0, stream>>>(counts, loss_acc, out1, out4);
}

// Round 14
// 684.030 us; speedup vs baseline: 1.2350x; 1.0026x over previous
//
#include <hip/hip_runtime.h>

#define N_TOK 32768
#define N_EMB 4096
#define DIM 256
#define NSTEP 128

typedef short bf16x8 __attribute__((ext_vector_type(8)));
typedef float f32x4 __attribute__((ext_vector_type(4)));
typedef unsigned short us8 __attribute__((ext_vector_type(8)));

// ---------------- ws layout (primary, ws_size >= 20 MB) ----------------
// [0, 16384)        counts    uint[4096]
// [16384, 16388)    loss_acc  float
// [16896, 33280)    e2_np     float[4096]
// [17 MB, 19 MB)    Wh        bf16[4096*256]  MFMA-shuffled
// Fallback (small ws): Wh in encodings region + separate k_onehot.

static __device__ __forceinline__ unsigned short f2bf(float f) {
    unsigned int u = __float_as_uint(f);
    u = (u + 0x7fffu + ((u >> 16) & 1u)) >> 16;   // RTN-even
    return (unsigned short)u;
}

// ---------------- numpy-pairwise fp32 row norms (r3-proven bit-exact) ------
__device__ __forceinline__ float pw128_sq(const float4* a4) {
#pragma clang fp contract(off)
    float4 v0 = a4[0], v1 = a4[1];
    float r0 = v0.x * v0.x, r1 = v0.y * v0.y, r2 = v0.z * v0.z, r3 = v0.w * v0.w;
    float r4 = v1.x * v1.x, r5 = v1.y * v1.y, r6 = v1.z * v1.z, r7 = v1.w * v1.w;
    #pragma unroll
    for (int i = 1; i < 16; ++i) {
        v0 = a4[2 * i]; v1 = a4[2 * i + 1];
        float s;
        s = v0.x * v0.x; r0 += s;
        s = v0.y * v0.y; r1 += s;
        s = v0.z * v0.z; r2 += s;
        s = v0.w * v0.w; r3 += s;
        s = v1.x * v1.x; r4 += s;
        s = v1.y * v1.y; r5 += s;
        s = v1.z * v1.z; r6 += s;
        s = v1.w * v1.w; r7 += s;
    }
    return ((r0 + r1) + (r2 + r3)) + ((r4 + r5) + (r6 + r7));
}

// ---- Wh-only prep: bf16 MFMA-shuffle + bit-exact row norms (r8-verified) ----
__global__ __launch_bounds__(256) void k_prep_w(const float* __restrict__ w,
                                                unsigned short* __restrict__ Wh,
                                                float* __restrict__ e2_np) {
    const int T = blockIdx.x;
    const int t = threadIdx.x, lane = t & 63, g = t >> 6;
    #pragma unroll
    for (int cc = 0; cc < 2; ++cc) {
        int C = g * 2 + cc;
        int row = T * 16 + (lane & 15);
        int col = C * 32 + (lane >> 4) * 8;
        const float* s = w + (size_t)row * DIM + col;
        us8 h;
        #pragma unroll
        for (int j = 0; j < 8; ++j) h[j] = f2bf(s[j]);
        *(us8*)(Wh + ((size_t)(T * 8 + C) * 64 + lane) * 8) = h;
    }
    if (t < 16) {
        int row = T * 16 + t;
        const float4* a = (const float4*)(w + (size_t)row * DIM);
        float lo = pw128_sq(a);
        float hi = pw128_sq(a + 32);
        e2_np[row] = lo + hi;
    }
}

// ---- fused MFMA scoring: r13's LDS GEMM loop + counted-vmcnt pipeline. ----
// r13 (685us, WIN) validated LDS staging; its residue: 5300 cy/step vs ~500
// of issue work = the per-step __syncthreads' vmcnt(0) drain (compiler emits
// it before s_barrier), paid 128x on the just-issued global_load_lds + NT
// drip ack. Fix per the T3/T4 recipe: TRIPLE buffer (staging 2 steps ahead),
// per-step ops exactly 5 (4 gl_lds + 1 NT drip), top-of-step
// s_waitcnt vmcnt(5) (= everything but the previous step's 5 ops complete ->
// this step's tile is staged) + RAW s_barrier; never drain to 0 in-loop.
// Tail steps re-stage tile (s+2)&127 into a dead buffer to keep the count
// uniform. clist/Red alias Bbuf post-loop (dummy stagings drain at the
// post-loop __syncthreads before the alias is written). LDS ~49.7 KB ->
// 3 blocks/CU (r11: occupancy is not the limiter). Fallback path (no enc)
// keeps a plain __syncthreads loop. All else r13-verbatim.
__global__ __launch_bounds__(256, 4) void k_score_mfma(
        const float* __restrict__ x, const float* __restrict__ w,
        const float* __restrict__ e2_np,
        const unsigned short* __restrict__ Wh,
        float* __restrict__ out_idx, unsigned int* __restrict__ counts,
        float* enc,                       // nullable: fused one-hot
        float* __restrict__ outq, float* __restrict__ loss_acc) {
    __shared__ __align__(16) short Bbuf[3][8192];   // 3 x 16 KB rotating
    __shared__ float x2s[32];
    __shared__ float Tmax[2][32];
    __shared__ unsigned int ccnt[32];
    __shared__ float sred[4];
    // post-loop aliases into Bbuf (dead after the main loop + barrier):
    int*   clist = (int*)&Bbuf[0][0];          // [32][16] = 2048 B
    float* Red_d = (float*)&Bbuf[0][1024];     // 1024 B (shorts 1024..1535)
    int*   Red_i = (int*)&Bbuf[0][1536];       // 1024 B

    const int t = threadIdx.x;
    const int wave = t >> 6, lane = t & 63;
    const int tok0 = blockIdx.x * 32;
    const int q = lane >> 4, c = lane & 15;
    const int mt = wave & 1, nb = wave >> 1;   // wave = (m-tile, n-half)

    // ---- prologue: stage tiles 0,1 into Bbuf[0],Bbuf[1] (r13-proven map) ----
    #pragma unroll
    for (int pb = 0; pb < 2; ++pb) {
        const unsigned short* sp = Wh + (size_t)pb * 8192 + wave * 512 + lane * 8;
        short* dp = &Bbuf[pb][wave * 512];
        #pragma unroll
        for (int k = 0; k < 4; ++k)
            __builtin_amdgcn_global_load_lds(
                (const __attribute__((address_space(1))) unsigned int*)(sp + k * 2048),
                (__attribute__((address_space(3))) unsigned int*)(dp + k * 2048),
                16, 0, 0);
    }

    // ---- A-fragment hoist (r13-verified mapping) ----
    bf16x8 ah[8];
    {
        const float* xrow = x + (size_t)(tok0 + mt * 16 + c) * DIM + q * 8;
        #pragma unroll
        for (int C = 0; C < 8; ++C) {
            float4 a = *(const float4*)(xrow + C * 32);
            float4 b = *(const float4*)(xrow + C * 32 + 4);
            us8 h;
            h[0] = f2bf(a.x); h[1] = f2bf(a.y); h[2] = f2bf(a.z); h[3] = f2bf(a.w);
            h[4] = f2bf(b.x); h[5] = f2bf(b.y); h[6] = f2bf(b.z); h[7] = f2bf(b.w);
            ah[C] = *(bf16x8*)&h;
        }
    }
    if (t < 32) {
        ccnt[t] = 0;
        const float4* a = (const float4*)(x + (size_t)(tok0 + t) * DIM);
        float lo = pw128_sq(a);
        float hi = pw128_sq(a + 32);
        x2s[t] = lo + hi;
    }
    __syncthreads();   // full drain: tiles 0,1 staged; A hoisted; norms ready

    f32x4* ez = enc ? (f32x4*)(enc + (size_t)tok0 * N_EMB) : (f32x4*)0;
    const f32x4 zf4 = {0.f, 0.f, 0.f, 0.f};

    float vmax[4], v2[4];
    #pragma unroll
    for (int r = 0; r < 4; ++r) { vmax[r] = -3.4e38f; v2[r] = -3.4e38f; }

    short* pr = &Bbuf[0][0];   // read buffer (tile s)
    short* pn = &Bbuf[1][0];   // tile s+1
    short* ps = &Bbuf[2][0];   // staging target (tile s+2)

    if (ez) {
        // ---- primary loop: counted vmcnt, raw barrier, 5 vmem ops/step ----
        for (int s = 0; s < NSTEP; ++s) {
            asm volatile("s_waitcnt vmcnt(5)" ::: "memory");
            __builtin_amdgcn_s_barrier();
            __builtin_amdgcn_sched_barrier(0);
            {   // stage tile (s+2)&127 (wrap keeps the op count uniform;
                // tail dummy lands in a dead buffer, drained before aliasing)
                int ts = (s + 2) & 127;
                const unsigned short* sp = Wh + (size_t)ts * 8192 + wave * 512 + lane * 8;
                short* dp = ps + wave * 512;
                #pragma unroll
                for (int k = 0; k < 4; ++k)
                    __builtin_amdgcn_global_load_lds(
                        (const __attribute__((address_space(1))) unsigned int*)(sp + k * 2048),
                        (__attribute__((address_space(3))) unsigned int*)(dp + k * 2048),
                        16, 0, 0);
            }
            __builtin_nontemporal_store(zf4, ez + s * 256 + t);   // one-hot drip
            f32x4 acc = {};
            #pragma unroll
            for (int C = 0; C < 8; ++C) {
                bf16x8 bh = *(const bf16x8*)(pr + ((size_t)(nb * 8 + C) * 64 + lane) * 8);
                acc = __builtin_amdgcn_mfma_f32_16x16x32_bf16(ah[C], bh, acc, 0, 0, 0);
            }
            #pragma unroll
            for (int r = 0; r < 4; ++r) {
                float p = __uint_as_float((__float_as_uint(acc[r]) & ~127u) | (unsigned)s);
                if (p > vmax[r]) { v2[r] = vmax[r]; vmax[r] = p; }
                else if (p > v2[r]) v2[r] = p;
            }
            short* tmp = pr; pr = pn; pn = ps; ps = tmp;
        }
    } else {
        // ---- fallback loop: plain __syncthreads (safe, no drip) ----
        for (int s = 0; s < NSTEP; ++s) {
            if (s + 2 < NSTEP) {
                const unsigned short* sp = Wh + (size_t)(s + 2) * 8192 + wave * 512 + lane * 8;
                short* dp = ps + wave * 512;
                #pragma unroll
                for (int k = 0; k < 4; ++k)
                    __builtin_amdgcn_global_load_lds(
                        (const __attribute__((address_space(1))) unsigned int*)(sp + k * 2048),
                        (__attribute__((address_space(3))) unsigned int*)(dp + k * 2048),
                        16, 0, 0);
            }
            f32x4 acc = {};
            #pragma unroll
            for (int C = 0; C < 8; ++C) {
                bf16x8 bh = *(const bf16x8*)(pr + ((size_t)(nb * 8 + C) * 64 + lane) * 8);
                acc = __builtin_amdgcn_mfma_f32_16x16x32_bf16(ah[C], bh, acc, 0, 0, 0);
            }
            #pragma unroll
            for (int r = 0; r < 4; ++r) {
                float p = __uint_as_float((__float_as_uint(acc[r]) & ~127u) | (unsigned)s);
                if (p > vmax[r]) { v2[r] = vmax[r]; vmax[r] = p; }
                else if (p > v2[r]) v2[r] = p;
            }
            __syncthreads();
            short* tmp = pr; pr = pn; pn = ps; ps = tmp;
        }
    }

    // ---- reduce over the 16 c-lanes of each q-group ----
    float rmax[4];
    #pragma unroll
    for (int r = 0; r < 4; ++r) rmax[r] = vmax[r];
    #pragma unroll
    for (int off = 1; off < 16; off <<= 1)
        #pragma unroll
        for (int r = 0; r < 4; ++r)
            rmax[r] = fmaxf(rmax[r], __shfl_xor(rmax[r], off));
    if (c == 0) {
        #pragma unroll
        for (int r = 0; r < 4; ++r)
            Tmax[nb][mt * 16 + q * 4 + r] = rmax[r];
    }
    __syncthreads();   // drains in-flight stagings/drips (vmcnt 0) + Tmax visible
    if (t < 32)
        Tmax[0][t] = fmaxf(Tmax[0][t], Tmax[1][t]) - 1.5e-4f;  // threshold
    __syncthreads();
    float thr[4];
    #pragma unroll
    for (int r = 0; r < 4; ++r)
        thr[r] = Tmax[0][mt * 16 + q * 4 + r];

    // ---- candidate push from registers (clist aliases dead Bbuf) ----
    #pragma unroll
    for (int r = 0; r < 4; ++r) {
        int tokl = mt * 16 + q * 4 + r;
        #pragma unroll
        for (int h = 0; h < 2; ++h) {
            float pv = h ? v2[r] : vmax[r];
            if (pv >= thr[r]) {
                int sid = (int)(__float_as_uint(pv) & 127u);
                int code = sid * 32 + nb * 16 + c;
                unsigned int p = atomicAdd(&ccnt[tokl], 1u);
                if (p < 16) clist[tokl * 16 + p] = code;
            }
        }
    }
    __syncthreads();

    // ---- np-fp32-exact refinement: 8 threads/token over the list ----
    {
        int token = t >> 3, slot = t & 7;
        int cnt = (int)ccnt[token]; if (cnt > 16) cnt = 16;
        float bd = 3.4e38f;
        int bi = 0x7fffffff;
        float x2 = x2s[token];
        const float4* xr = (const float4*)(x + (size_t)(tok0 + token) * DIM);
        for (int k = slot; k < cnt; k += 8) {
            int code = clist[token * 16 + k];
            const float4* wr = (const float4*)(w + (size_t)code * DIM);
            double dot = 0.0;
            for (int g = 0; g < 64; ++g) {
                float4 xv = xr[g];
                float4 wv = wr[g];
                dot += (double)xv.x * (double)wv.x;
                dot += (double)xv.y * (double)wv.y;
                dot += (double)xv.z * (double)wv.z;
                dot += (double)xv.w * (double)wv.w;
            }
            {
#pragma clang fp contract(off)
                float M  = (float)dot;          // BLAS sgemm entry (~2e-9)
                float S  = x2 + e2_np[code];    // np broadcast add (fp32)
                float dd = S - 2.0f * M;        // fp32 sub -> ulp bucket
                if (dd < bd || (dd == bd && code < bi)) { bd = dd; bi = code; }
            }
        }
        Red_d[token * 8 + slot] = bd;
        Red_i[token * 8 + slot] = bi;
    }
    __syncthreads();
    if (t < 32) {
        float fv = Red_d[t * 8];
        int   fi = Red_i[t * 8];
        #pragma unroll
        for (int k = 1; k < 8; ++k) {
            float v = Red_d[t * 8 + k];
            int  ii = Red_i[t * 8 + k];
            if (v < fv || (v == fv && ii < fi)) { fv = v; fi = ii; }
        }
        out_idx[tok0 + t] = (float)fi;
        atomicAdd(&counts[fi], 1u);
        ccnt[t] = (unsigned int)fi;   // publish for epilogue
    }
    __syncthreads();

    // ---- epilogue: 1.0f scatter + quantized gather + commitment loss ----
    {
        int token = t >> 3, slot = t & 7;
        int fi = (int)ccnt[token];
        // drips drained at the post-loop __syncthreads (vmcnt 0);
        // same-XCD L2 ordering makes this 1.0f land after them.
        if (enc && slot == 0)
            __builtin_nontemporal_store(1.0f, enc + (size_t)(tok0 + token) * N_EMB + fi);
        const f32x4* wr = (const f32x4*)(w + (size_t)fi * DIM);
        const f32x4* xr = (const f32x4*)(x + (size_t)(tok0 + token) * DIM);
        f32x4* oq = (f32x4*)(outq + (size_t)(tok0 + token) * DIM);
        float sse = 0.f;
        #pragma unroll
        for (int g0 = 0; g0 < 8; ++g0) {
            int g = slot * 8 + g0;
            f32x4 qv = wr[g];
            f32x4 xv = xr[g];
            __builtin_nontemporal_store(qv, oq + g);
            float dx = qv.x - xv.x, dy = qv.y - xv.y;
            float dz = qv.z - xv.z, dw = qv.w - xv.w;
            sse += dx * dx + dy * dy + dz * dz + dw * dw;
        }
        #pragma unroll
        for (int off = 32; off > 0; off >>= 1) sse += __shfl_down(sse, off, 64);
        if (lane == 0) sred[wave] = sse;
    }
    __syncthreads();
    if (t == 0)
        atomicAdd(loss_acc, sred[0] + sred[1] + sred[2] + sred[3]);
}

// ---------------- one-hot encodings (fallback path only) ----------------
__global__ __launch_bounds__(256) void k_onehot(const float* __restrict__ out_idx,
                                                float* __restrict__ enc) {
    int token = blockIdx.x;
    int idx = (int)out_idx[token];
    float4* row = (float4*)(enc + (size_t)token * N_EMB);
    #pragma unroll
    for (int p = 0; p < 4; ++p) {
        int g = threadIdx.x + 256 * p;
        float4 v = make_float4(0.f, 0.f, 0.f, 0.f);
        int d0 = g * 4;
        if (idx >= d0 && idx < d0 + 4) ((float*)&v)[idx - d0] = 1.0f;
        row[g] = v;
    }
}

// ---------------- perplexity + loss finalize ----------------
__global__ __launch_bounds__(256) void k_final(const unsigned int* __restrict__ counts,
                                               const float* __restrict__ loss_acc,
                                               float* __restrict__ out_perp,
                                               float* __restrict__ out_loss) {
    __shared__ float sred[4];
    int t = threadIdx.x;
    float h = 0.f;
    for (int k = t; k < N_EMB; k += 256) {
        float p = (float)counts[k] * (1.0f / N_TOK);
        h += p * logf(p + 1e-10f);
    }
    #pragma unroll
    for (int off = 32; off > 0; off >>= 1) h += __shfl_down(h, off, 64);
    if ((t & 63) == 0) sred[t >> 6] = h;
    __syncthreads();
    if (t == 0) {
        float s = sred[0] + sred[1] + sred[2] + sred[3];
        *out_perp = expf(-s);
        *out_loss = loss_acc[0] * 1.25f / 8388608.0f;
    }
}

extern "C" void kernel_launch(void* const* d_in, const int* in_sizes, int n_in,
                              void* d_out, int out_size, void* d_ws, size_t ws_size,
                              hipStream_t stream) {
    const float* x = (const float*)d_in[0];
    const float* w = (const float*)d_in[1];
    float* out  = (float*)d_out;
    float* out0 = out;                       // quantized_st [32768*256]
    float* out1 = out0 + 8388608;            // perplexity   [1]
    float* out2 = out1 + 1;                  // encodings    [32768*4096]
    float* out3 = out2 + 134217728;          // indices      [32768] (as float)
    float* out4 = out3 + 32768;              // loss         [1]

    unsigned int* counts = (unsigned int*)d_ws;
    float* loss_acc = (float*)((char*)d_ws + 16384);
    float* e2_np    = (float*)((char*)d_ws + 16896);

    // Primary: Wh in d_ws, enc zeroed by the drip inside the score loop +
    // 1.0f scatter. Fallback (small ws): Wh aliases out2 -> no fused enc,
    // full-row k_onehot after score.
    bool big_ws = ws_size >= (size_t)(20u * 1024u * 1024u);
    unsigned short* Wh;
    float* enc_arg;
    if (big_ws) {
        Wh = (unsigned short*)((char*)d_ws + 17u * 1024u * 1024u);   // 2 MB
        enc_arg = out2;
    } else {
        uintptr_t sb = ((uintptr_t)out2 + 255) & ~(uintptr_t)255;
        Wh = (unsigned short*)sb;
        enc_arg = nullptr;
    }

    hipMemsetAsync(d_ws, 0, 16640, stream);
    k_prep_w<<<N_EMB / 16, 256, 0, stream>>>(w, Wh, e2_np);
    k_score_mfma<<<N_TOK / 32, 256, 0, stream>>>(x, w, e2_np, Wh,
                                                 out3, counts, enc_arg,
                                                 out0, loss_acc);
    if (!big_ws)
        k_onehot<<<N_TOK, 256, 0, stream>>>(out3, out2);
    k_final<<<1, 256, 0, stream>>>(counts, loss_acc, out1, out4);
}